// Round 7
// baseline (326.962 us; speedup 1.0000x reference)
//
#include <hip/hip_runtime.h>
#include <cmath>

#define B 4
#define NQ 128
#define NK 1024
#define HD 256
#define DV 256
#define NBLK 256
#define NTHR 256

// One kernel, six phases. grid-wide sync = hand-rolled sense-reversing
// barrier (system-scope atomics + __threadfence on both sides, per
// Guideline 16: per-XCD L2s are not coherent; the coherence point is the
// Infinity Cache, which system-scope atomics/fences traverse).
// Rationale for single launch: measured ~23 us/launch overhead
// (R0: 152us @ 6 launches, R5: 129us @ 5 launches, same ~15us work).
union SMem {
    struct { float sX[64][68]; float sW[64][68]; } proj;                 // 34.8 KB
    struct { float s_q[32][68]; float s_k[32][68]; float s_w[64]; } sc;  // 17.7 KB
    struct { float s_a[16][128]; } pv;                                    // 8 KB
    struct { float redm[4]; float reds[4]; } sm;
};

__device__ __forceinline__ void grid_sync(unsigned* counter, unsigned* gen)
{
    __syncthreads();
    if (threadIdx.x == 0) {
        __threadfence();   // release: make all prior writes visible at coherence point
        unsigned g = __atomic_load_n(gen, __ATOMIC_RELAXED);
        if (__atomic_fetch_add(counter, 1u, __ATOMIC_ACQ_REL) == NBLK - 1u) {
            __atomic_store_n(counter, 0u, __ATOMIC_RELAXED);
            __atomic_fetch_add(gen, 1u, __ATOMIC_RELEASE);
        } else {
            while (__atomic_load_n(gen, __ATOMIC_ACQUIRE) == g)
                __builtin_amdgcn_s_sleep(2);
        }
        __threadfence();   // acquire: invalidate stale cached lines before next phase
    }
    __syncthreads();
}

__global__ __launch_bounds__(NTHR) void mega_attn(
    const float* __restrict__ queries, const float* __restrict__ keys,
    const float* __restrict__ values, const int* __restrict__ valid_lens,
    const float* __restrict__ Wq, const float* __restrict__ Wk,
    const float* __restrict__ wv, float* __restrict__ out,
    float* __restrict__ Eq, float* __restrict__ Ek,
    float* __restrict__ Qpart, float* __restrict__ scores,
    float* __restrict__ partial, unsigned* __restrict__ bar)
{
    unsigned* counter = bar;
    unsigned* gen     = bar + 1;
    __shared__ SMem sm_;
    const int tid = threadIdx.x;
    const int bid = blockIdx.x;
    const int ty = tid >> 4, tx = tid & 15;

    // ================= Phase 1a: K-projection, one 64x64 tile/block =======
    // Ek[m,h] = exp(2 * keys[m,:]·Wk[h,:]); 64 m-tiles x 4 h-tiles = 256.
    {
        const int bm = (bid >> 2) * 64;
        const int bh = (bid & 3) * 64;
        const int lr = tid >> 2;
        const int lc = (tid & 3) << 4;
        float acc[4][4] = {};
        for (int ks = 0; ks < HD; ks += 64) {
            #pragma unroll
            for (int j = 0; j < 4; ++j) {
                const int d = lc + j * 4;
                float4 xv = *(const float4*)&keys[(size_t)(bm + lr) * HD + ks + d];
                float4 wm = *(const float4*)&Wk [(size_t)(bh + lr) * HD + ks + d];
                sm_.proj.sX[d + 0][lr] = xv.x; sm_.proj.sX[d + 1][lr] = xv.y;
                sm_.proj.sX[d + 2][lr] = xv.z; sm_.proj.sX[d + 3][lr] = xv.w;
                sm_.proj.sW[d + 0][lr] = wm.x; sm_.proj.sW[d + 1][lr] = wm.y;
                sm_.proj.sW[d + 2][lr] = wm.z; sm_.proj.sW[d + 3][lr] = wm.w;
            }
            __syncthreads();
            #pragma unroll 8
            for (int kk = 0; kk < 64; ++kk) {
                float4 a4 = *(const float4*)&sm_.proj.sX[kk][ty * 4];
                float4 b4 = *(const float4*)&sm_.proj.sW[kk][tx * 4];
                float av[4] = {a4.x, a4.y, a4.z, a4.w};
                float bv[4] = {b4.x, b4.y, b4.z, b4.w};
                #pragma unroll
                for (int i = 0; i < 4; ++i)
                    #pragma unroll
                    for (int j = 0; j < 4; ++j)
                        acc[i][j] = fmaf(av[i], bv[j], acc[i][j]);
            }
            __syncthreads();
        }
        const int m0 = bm + ty * 4, h0 = bh + tx * 4;
        #pragma unroll
        for (int i = 0; i < 4; ++i) {
            float4 e4 = {__expf(2.0f * acc[i][0]), __expf(2.0f * acc[i][1]),
                         __expf(2.0f * acc[i][2]), __expf(2.0f * acc[i][3])};
            *(float4*)&Ek[(size_t)(m0 + i) * HD + h0] = e4;
        }
    }

    // ================= Phase 1a': Q-projection, K-split subtile/block =====
    // 32 (64x64) tiles x 8 K-slices of 32 = 256 balanced sub-tiles -> Qpart.
    {
        const int s  = bid & 7;
        const int tq = bid >> 3;           // 0..31
        const int bm = (tq >> 2) * 64;     // query row base (0..448)
        const int bh = (tq & 3) * 64;
        const int k0 = s * 32;
        const int lr  = tid >> 2;          // m-row 0..63
        const int lc2 = (tid & 3) * 8;     // 8 k-cols per thread
        __syncthreads();
        {
            float4 xa = *(const float4*)&queries[(size_t)(bm + lr) * HD + k0 + lc2];
            float4 xb = *(const float4*)&queries[(size_t)(bm + lr) * HD + k0 + lc2 + 4];
            float4 wa = *(const float4*)&Wq[(size_t)(bh + lr) * HD + k0 + lc2];
            float4 wb = *(const float4*)&Wq[(size_t)(bh + lr) * HD + k0 + lc2 + 4];
            sm_.proj.sX[lc2 + 0][lr] = xa.x; sm_.proj.sX[lc2 + 1][lr] = xa.y;
            sm_.proj.sX[lc2 + 2][lr] = xa.z; sm_.proj.sX[lc2 + 3][lr] = xa.w;
            sm_.proj.sX[lc2 + 4][lr] = xb.x; sm_.proj.sX[lc2 + 5][lr] = xb.y;
            sm_.proj.sX[lc2 + 6][lr] = xb.z; sm_.proj.sX[lc2 + 7][lr] = xb.w;
            sm_.proj.sW[lc2 + 0][lr] = wa.x; sm_.proj.sW[lc2 + 1][lr] = wa.y;
            sm_.proj.sW[lc2 + 2][lr] = wa.z; sm_.proj.sW[lc2 + 3][lr] = wa.w;
            sm_.proj.sW[lc2 + 4][lr] = wb.x; sm_.proj.sW[lc2 + 5][lr] = wb.y;
            sm_.proj.sW[lc2 + 6][lr] = wb.z; sm_.proj.sW[lc2 + 7][lr] = wb.w;
        }
        __syncthreads();
        float acc[4][4] = {};
        #pragma unroll 8
        for (int kk = 0; kk < 32; ++kk) {
            float4 a4 = *(const float4*)&sm_.proj.sX[kk][ty * 4];
            float4 b4 = *(const float4*)&sm_.proj.sW[kk][tx * 4];
            float av[4] = {a4.x, a4.y, a4.z, a4.w};
            float bv[4] = {b4.x, b4.y, b4.z, b4.w};
            #pragma unroll
            for (int i = 0; i < 4; ++i)
                #pragma unroll
                for (int j = 0; j < 4; ++j)
                    acc[i][j] = fmaf(av[i], bv[j], acc[i][j]);
        }
        float* qp = &Qpart[((size_t)(s * 32 + tq)) * 64 * 64];
        #pragma unroll
        for (int i = 0; i < 4; ++i) {
            float4 p4 = {acc[i][0], acc[i][1], acc[i][2], acc[i][3]};
            *(float4*)&qp[(ty * 4 + i) * 64 + tx * 4] = p4;
        }
    }
    grid_sync(counter, gen);   // S1: Qpart, Ek complete

    // ================= Phase 1b: combine Q partials + exp -> Eq ===========
    {
        #pragma unroll
        for (int rep = 0; rep < 2; ++rep) {
            const int q = bid * 2 + rep;       // flat row 0..511
            const int h = tid;
            const int tq = (q >> 6) * 4 + (h >> 6);
            const int qm = q & 63, hm = h & 63;
            float ssum = 0.f;
            #pragma unroll
            for (int s2 = 0; s2 < 8; ++s2)
                ssum += Qpart[(((size_t)(s2 * 32 + tq)) * 64 + qm) * 64 + hm];
            Eq[(size_t)q * HD + h] = __expf(2.0f * ssum);
        }
    }
    grid_sync(counter, gen);   // S2: Eq complete

    // ================= Phase 2: scores, 2 (32x32) tiles per block =========
    // scores' = sum_h w2[h]*rcp(1+eq*ek), w2=-2wv (quad common-denominator).
    for (int rep = 0; rep < 2; ++rep) {
        const int tile = bid + rep * NBLK;
        const int kb = (tile & 31) * 32;
        const int qb = ((tile >> 5) & 3) * 32;
        const int b  = tile >> 7;
        float a00 = 0.f, a01 = 0.f, a10 = 0.f, a11 = 0.f;
        const size_t qbase = ((size_t)b * NQ + qb) * HD;
        const size_t kbase = ((size_t)b * NK + kb) * HD;
        const int srow = tid >> 3;
        const int scol = (tid & 7) << 3;
        __syncthreads();
        for (int hc = 0; hc < HD; hc += 64) {
            {
                const float* qp = &Eq[qbase + (size_t)srow * HD + hc + scol];
                const float* kp = &Ek[kbase + (size_t)srow * HD + hc + scol];
                float4 q0 = *(const float4*)qp;
                float4 q1 = *(const float4*)(qp + 4);
                float4 k0 = *(const float4*)kp;
                float4 k1 = *(const float4*)(kp + 4);
                *(float4*)&sm_.sc.s_q[srow][scol]     = q0;
                *(float4*)&sm_.sc.s_q[srow][scol + 4] = q1;
                *(float4*)&sm_.sc.s_k[srow][scol]     = k0;
                *(float4*)&sm_.sc.s_k[srow][scol + 4] = k1;
                if (tid < 16) {
                    float4 w = *(const float4*)&wv[hc + tid * 4];
                    sm_.sc.s_w[tid * 4 + 0] = -2.0f * w.x;
                    sm_.sc.s_w[tid * 4 + 1] = -2.0f * w.y;
                    sm_.sc.s_w[tid * 4 + 2] = -2.0f * w.z;
                    sm_.sc.s_w[tid * 4 + 3] = -2.0f * w.w;
                }
            }
            __syncthreads();
            #pragma unroll
            for (int i = 0; i < 16; ++i) {
                const int h4 = i << 2;
                const float4 W4 = *(const float4*)&sm_.sc.s_w[h4];
                const float4 Q0 = *(const float4*)&sm_.sc.s_q[ty][h4];
                const float4 Q1 = *(const float4*)&sm_.sc.s_q[ty + 16][h4];
                const float4 K0 = *(const float4*)&sm_.sc.s_k[tx][h4];
                const float4 K1 = *(const float4*)&sm_.sc.s_k[tx + 16][h4];
                #pragma unroll
                for (int pair = 0; pair < 4; ++pair) {
                    const float4* Qp = (pair < 2) ? &Q0 : &Q1;
                    const float4* Kp = (pair & 1) ? &K1 : &K0;
                    float d0 = fmaf(Qp->x, Kp->x, 1.0f);
                    float d1 = fmaf(Qp->y, Kp->y, 1.0f);
                    float d2 = fmaf(Qp->z, Kp->z, 1.0f);
                    float d3 = fmaf(Qp->w, Kp->w, 1.0f);
                    float n01 = fmaf(W4.x, d1, W4.y * d0);
                    float d01 = d0 * d1;
                    float n23 = fmaf(W4.z, d3, W4.w * d2);
                    float d23 = d2 * d3;
                    float n  = fmaf(n01, d23, n23 * d01);
                    float dd = d01 * d23;
                    float r  = fmaf(n, __builtin_amdgcn_rcpf(dd), 0.0f);
                    if (pair == 0) a00 += r;
                    else if (pair == 1) a01 += r;
                    else if (pair == 2) a10 += r;
                    else a11 += r;
                }
            }
            __syncthreads();
        }
        const size_t r0 = ((size_t)b * NQ + qb + ty) * NK;
        const size_t r1 = ((size_t)b * NQ + qb + ty + 16) * NK;
        scores[r0 + kb + tx]      = a00;
        scores[r0 + kb + tx + 16] = a01;
        scores[r1 + kb + tx]      = a10;
        scores[r1 + kb + tx + 16] = a11;
    }
    grid_sync(counter, gen);   // S3: scores complete

    // ================= Phase 3: masked softmax, 2 rows per block ==========
    for (int rep = 0; rep < 2; ++rep) {
        const int row = bid * 2 + rep;
        const int b = row >> 7;
        const int valid = valid_lens[b];
        float* s = scores + (size_t)row * NK;
        float4 v = *(const float4*)&s[tid * 4];
        float x[4] = {v.x, v.y, v.z, v.w};
        #pragma unroll
        for (int j = 0; j < 4; ++j) {
            const int k = tid * 4 + j;
            if (k >= valid) x[j] = -1e6f;
        }
        float m = fmaxf(fmaxf(x[0], x[1]), fmaxf(x[2], x[3]));
        #pragma unroll
        for (int off = 32; off >= 1; off >>= 1)
            m = fmaxf(m, __shfl_xor(m, off));
        const int wid = tid >> 6, lane = tid & 63;
        if (lane == 0) sm_.sm.redm[wid] = m;
        __syncthreads();
        m = fmaxf(fmaxf(sm_.sm.redm[0], sm_.sm.redm[1]),
                  fmaxf(sm_.sm.redm[2], sm_.sm.redm[3]));
        float p[4], psum = 0.f;
        #pragma unroll
        for (int j = 0; j < 4; ++j) { p[j] = __expf(x[j] - m); psum += p[j]; }
        #pragma unroll
        for (int off = 32; off >= 1; off >>= 1)
            psum += __shfl_xor(psum, off);
        if (lane == 0) sm_.sm.reds[wid] = psum;
        __syncthreads();
        const float total = sm_.sm.reds[0] + sm_.sm.reds[1] +
                            sm_.sm.reds[2] + sm_.sm.reds[3];
        const float inv = 1.0f / total;
        float4 o = {p[0] * inv, p[1] * inv, p[2] * inv, p[3] * inv};
        *(float4*)&s[tid * 4] = o;
        __syncthreads();
    }
    grid_sync(counter, gen);   // S4: attn complete

    // ================= Phase 4: PV partial, 1 (16q x 128k) slice/block ====
    {
        const int ks = bid & 7, qg = (bid >> 3) & 7, b = bid >> 6;
        const int q0 = qg * 16;
        const int k0 = ks * 128;
        #pragma unroll
        for (int f0 = 0; f0 < 2; ++f0) {
            const int f = tid + f0 * 256;
            const int row = f >> 5;
            const int col = (f & 31) << 2;
            *(float4*)&sm_.pv.s_a[row][col] =
                *(const float4*)&scores[((size_t)b * NQ + q0 + row) * NK + k0 + col];
        }
        __syncthreads();
        float acc[16] = {};
        #pragma unroll 8
        for (int k = 0; k < 128; ++k) {
            const float va = values[((size_t)b * NK + k0 + k) * DV + tid];
            #pragma unroll
            for (int q = 0; q < 16; ++q)
                acc[q] = fmaf(sm_.pv.s_a[q][k], va, acc[q]);
        }
        const size_t pbase = (size_t)ks * (B * NQ * DV) +
                             ((size_t)b * NQ + q0) * DV + tid;
        #pragma unroll
        for (int q = 0; q < 16; ++q)
            partial[pbase + (size_t)q * DV] = acc[q];
    }
    grid_sync(counter, gen);   // S5: partials complete

    // ================= Phase 5: reduce 8 partials -> out ==================
    {
        #pragma unroll
        for (int rep = 0; rep < 2; ++rep) {
            const int i = bid * 512 + rep * 256 + tid;
            float ssum = 0.f;
            #pragma unroll
            for (int p = 0; p < 8; ++p)
                ssum += partial[(size_t)p * (B * NQ * DV) + i];
            out[i] = ssum;
        }
    }
}

// ---------------------------------------------------------------------------
extern "C" void kernel_launch(void* const* d_in, const int* in_sizes, int n_in,
                              void* d_out, int out_size, void* d_ws, size_t ws_size,
                              hipStream_t stream) {
    const float* queries    = (const float*)d_in[0];
    const float* keys       = (const float*)d_in[1];
    const float* values     = (const float*)d_in[2];
    const int*   valid_lens = (const int*)  d_in[3];
    const float* Wq         = (const float*)d_in[4];
    const float* Wk         = (const float*)d_in[5];
    const float* wv         = (const float*)d_in[6];
    float* out = (float*)d_out;

    float* ws      = (float*)d_ws;
    float* Eq      = ws;                               // 512*256      = 131072
    float* Ek      = Eq + (size_t)B * NQ * HD;         // 4096*256     = 1048576
    float* Qpart   = Ek + (size_t)B * NK * HD;         // 8*32*64*64   = 1048576
    float* scores  = Qpart + (size_t)8 * 32 * 64 * 64; // 512*1024     = 524288
    float* partial = scores + (size_t)B * NQ * NK;     // 8*4*128*256  = 1048576
    unsigned* bar  = (unsigned*)(partial + (size_t)8 * B * NQ * DV); // 2 words

    // zero the barrier state (counter, generation) — ws is poisoned 0xAA.
    hipMemsetAsync(bar, 0, 2 * sizeof(unsigned), stream);

    mega_attn<<<dim3(NBLK), dim3(NTHR), 0, stream>>>(
        queries, keys, values, valid_lens, Wq, Wk, wv, out,
        Eq, Ek, Qpart, scores, partial, bar);
}